// Round 1
// baseline (562.483 us; speedup 1.0000x reference)
//
#include <hip/hip_runtime.h>

#define HW 4096
#define CCH 512
#define SDIM 64
#define BDIM 8

// K1: projection  ap[hw][b][s] = sum_c x[b][c][hw] * w[s][c]
__global__ __launch_bounds__(256) void proj_kernel(const float* __restrict__ x,
                                                   const float* __restrict__ w,
                                                   float* __restrict__ ap) {
  __shared__ float Xs[64 * 64];  // [cc][hw]
  const int hw0 = blockIdx.x * 64;
  const int b = blockIdx.y;
  const int tid = threadIdx.x;
  const int lane = tid & 63;
  const int sq = __builtin_amdgcn_readfirstlane(tid >> 6);  // wave id 0..3 -> s group
  float acc[16] = {};
  for (int c0 = 0; c0 < CCH; c0 += 64) {
    __syncthreads();
#pragma unroll
    for (int it = 0; it < 4; ++it) {
      int f = (it * 256 + tid) * 4;
      int cc = f >> 6, i = f & 63;
      *reinterpret_cast<float4*>(&Xs[f]) =
          *reinterpret_cast<const float4*>(&x[(size_t)(b * CCH + c0 + cc) * HW + hw0 + i]);
    }
    __syncthreads();
#pragma unroll 2
    for (int cq = 0; cq < 64; cq += 4) {
      float x0 = Xs[(cq + 0) * 64 + lane];
      float x1 = Xs[(cq + 1) * 64 + lane];
      float x2 = Xs[(cq + 2) * 64 + lane];
      float x3 = Xs[(cq + 3) * 64 + lane];
#pragma unroll
      for (int j = 0; j < 16; ++j) {
        const float4 wv = *reinterpret_cast<const float4*>(&w[(size_t)(sq * 16 + j) * CCH + c0 + cq]);
        acc[j] = fmaf(x3, wv.w, fmaf(x2, wv.z, fmaf(x1, wv.y, fmaf(x0, wv.x, acc[j]))));
      }
    }
  }
  float* dst = &ap[(size_t)(hw0 + lane) * (BDIM * SDIM) + b * SDIM + sq * 16];
#pragma unroll
  for (int j4 = 0; j4 < 4; ++j4) {
    float4 o = make_float4(acc[j4 * 4 + 0], acc[j4 * 4 + 1], acc[j4 * 4 + 2], acc[j4 * 4 + 3]);
    *reinterpret_cast<float4*>(&dst[j4 * 4]) = o;
  }
}

// K2: rD[br][h][s][t] = 1 / sum_w exp( sum_b A[h,w,b,s]*B[h,w,b,t] )
__global__ __launch_bounds__(512) void denom_kernel(const float* __restrict__ ap,
                                                    float* __restrict__ rD) {
  __shared__ float As[8 * 64];
  __shared__ float Bs[8 * 64];
  const int h = blockIdx.x, br = blockIdx.y;
  const float* A  = ap + ((size_t)br * HW + (size_t)h * 64) * (BDIM * SDIM);
  const float* Bp = ap + ((size_t)((br + 1) % 3) * HW + (size_t)h * 64) * (BDIM * SDIM);
  const int tid = threadIdx.x;
  const int t = tid & 63;
  const int sb = (tid >> 6) * 8;
  float D[8] = {};
  for (int w = 0; w < 64; ++w) {
    __syncthreads();
    As[tid] = A[w * (BDIM * SDIM) + tid];
    Bs[tid] = Bp[w * (BDIM * SDIM) + tid];
    __syncthreads();
    float bv[8];
#pragma unroll
    for (int b = 0; b < 8; ++b) bv[b] = Bs[b * 64 + t];
#pragma unroll
    for (int j = 0; j < 8; ++j) {
      float m = 0.f;
#pragma unroll
      for (int b = 0; b < 8; ++b) m = fmaf(As[b * 64 + sb + j], bv[b], m);
      D[j] += __expf(m);
    }
  }
#pragma unroll
  for (int j = 0; j < 8; ++j)
    rD[((size_t)(br * 64 + h) * 64 + sb + j) * 64 + t] = 1.0f / D[j];
}

// K3: on[br][hw][b][s] = o[s][b]/N[b], o = mtilde * C^T
__global__ __launch_bounds__(256) void attn_kernel(const float* __restrict__ ap,
                                                   const float* __restrict__ rD,
                                                   float* __restrict__ on) {
  __shared__ float As[8 * 64], Bs[8 * 64], Cs[8 * 64];
  __shared__ float Ms[64 * 68];  // [s][t] padded
  const int wc = blockIdx.x, h = blockIdx.y, br = blockIdx.z;
  const float* A  = ap + ((size_t)br * HW + h * 64) * 512;
  const float* Bp = ap + ((size_t)((br + 1) % 3) * HW + h * 64) * 512;
  const float* Cp = ap + ((size_t)((br + 2) % 3) * HW + h * 64) * 512;
  const float* rDp = rD + (size_t)(br * 64 + h) * 4096;  // [s][t]
  const int tid = threadIdx.x;
  for (int w = wc * 8; w < wc * 8 + 8; ++w) {
    __syncthreads();
#pragma unroll
    for (int it = 0; it < 2; ++it) {
      int idx = it * 256 + tid;
      As[idx] = A[w * 512 + idx];
      Bs[idx] = Bp[w * 512 + idx];
      Cs[idx] = Cp[w * 512 + idx];
    }
    __syncthreads();
    {
      const int t = tid & 63, sg = tid >> 6;
      float bv[8];
#pragma unroll
      for (int b = 0; b < 8; ++b) bv[b] = Bs[b * 64 + t];
#pragma unroll
      for (int j = 0; j < 16; ++j) {
        int s = sg * 16 + j;
        float m = 0.f;
#pragma unroll
        for (int b = 0; b < 8; ++b) m = fmaf(As[b * 64 + s], bv[b], m);
        Ms[s * 68 + t] = __expf(m) * rDp[s * 64 + t];
      }
    }
    __syncthreads();
    const int s2 = tid & 63, bq = tid >> 6;
    float o0 = 0.f, o1 = 0.f;
#pragma unroll
    for (int tt = 0; tt < 64; tt += 4) {
      float4 mv = *reinterpret_cast<const float4*>(&Ms[s2 * 68 + tt]);
      float4 c0 = *reinterpret_cast<const float4*>(&Cs[bq * 64 + tt]);
      float4 c1 = *reinterpret_cast<const float4*>(&Cs[(bq + 4) * 64 + tt]);
      o0 = fmaf(mv.w, c0.w, fmaf(mv.z, c0.z, fmaf(mv.y, c0.y, fmaf(mv.x, c0.x, o0))));
      o1 = fmaf(mv.w, c1.w, fmaf(mv.z, c1.z, fmaf(mv.y, c1.y, fmaf(mv.x, c1.x, o1))));
    }
    // N[b] = sum_s o[s][b]  (butterfly over the 64 lanes = s)
    float n0 = o0, n1 = o1;
#pragma unroll
    for (int off = 32; off > 0; off >>= 1) {
      n0 += __shfl_xor(n0, off);
      n1 += __shfl_xor(n1, off);
    }
    const float r0 = 1.0f / n0, r1 = 1.0f / n1;
    const size_t ob = ((size_t)br * HW + h * 64 + w) * 512;
    on[ob + (size_t)bq * 64 + s2] = o0 * r0;
    on[ob + (size_t)(bq + 4) * 64 + s2] = o1 * r1;
  }
}

// K4: out[brb][c][hw] = sum_s on[br][hw][b][s] * wl[c][s]
__global__ __launch_bounds__(256) void out_kernel(const float* __restrict__ on,
                                                  const float* __restrict__ wl,
                                                  float* __restrict__ out) {
  __shared__ float Ol[64 * 68];  // [hw][s] padded
  const int c0 = blockIdx.x * 64;
  const int hw0 = blockIdx.y * 64;
  const int brb = blockIdx.z;
  const int br = brb >> 3, b = brb & 7;
  const int tid = threadIdx.x;
  const int lane = tid & 63;
  const int cq = __builtin_amdgcn_readfirstlane(tid >> 6);
#pragma unroll
  for (int it = 0; it < 4; ++it) {
    int f = (it * 256 + tid) * 4;
    int i = f >> 6, s = f & 63;
    *reinterpret_cast<float4*>(&Ol[i * 68 + s]) =
        *reinterpret_cast<const float4*>(&on[((size_t)(br * HW + hw0 + i) * 8 + b) * 64 + s]);
  }
  __syncthreads();
  float4 orow[16];
#pragma unroll
  for (int qd = 0; qd < 16; ++qd)
    orow[qd] = *reinterpret_cast<const float4*>(&Ol[lane * 68 + qd * 4]);
  float acc[16];
#pragma unroll
  for (int j = 0; j < 16; ++j) {
    const float* wrow = &wl[(size_t)(c0 + cq * 16 + j) * 64];
    float a = 0.f;
#pragma unroll
    for (int qd = 0; qd < 16; ++qd) {
      float4 wv = *reinterpret_cast<const float4*>(&wrow[qd * 4]);
      a = fmaf(orow[qd].w, wv.w, fmaf(orow[qd].z, wv.z, fmaf(orow[qd].y, wv.y, fmaf(orow[qd].x, wv.x, a))));
    }
    acc[j] = a;
  }
#pragma unroll
  for (int j = 0; j < 16; ++j)
    out[((size_t)brb * 512 + c0 + cq * 16 + j) * HW + hw0 + lane] = acc[j];
}

extern "C" void kernel_launch(void* const* d_in, const int* in_sizes, int n_in,
                              void* d_out, int out_size, void* d_ws, size_t ws_size,
                              hipStream_t stream) {
  const float* q  = (const float*)d_in[0];
  const float* k  = (const float*)d_in[1];
  const float* v  = (const float*)d_in[2];
  const float* Wq = (const float*)d_in[3];
  const float* Wk = (const float*)d_in[4];
  const float* Wv = (const float*)d_in[5];
  const float* Wl = (const float*)d_in[6];
  float* out = (float*)d_out;

  float* ap = (float*)d_ws;                         // 3*HW*B*S floats = 25.2 MB
  float* rD = ap + (size_t)3 * HW * 512;            // 3*64*64*64 floats = 3.1 MB
  float* on = rD + (size_t)3 * 64 * 64 * 64;        // 3*HW*B*S floats = 25.2 MB

  dim3 gp(64, 8);
  proj_kernel<<<gp, 256, 0, stream>>>(q, Wq, ap);
  proj_kernel<<<gp, 256, 0, stream>>>(k, Wk, ap + (size_t)HW * 512);
  proj_kernel<<<gp, 256, 0, stream>>>(v, Wv, ap + (size_t)2 * HW * 512);

  denom_kernel<<<dim3(64, 3), 512, 0, stream>>>(ap, rD);
  attn_kernel<<<dim3(8, 64, 3), 256, 0, stream>>>(ap, rD, on);
  out_kernel<<<dim3(8, 64, 24), 256, 0, stream>>>(on, Wl, out);
}

// Round 3
// 399.744 us; speedup vs baseline: 1.4071x; 1.4071x over previous
//
#include <hip/hip_runtime.h>

#define HW 4096
#define CCH 512
#define SDIM 64
#define BDIM 8

// K1: fused projection over all 3 branches:
//   ap[br][hw][b][s] = sum_c x_br[b][c][hw] * w_br[s][c]
__global__ __launch_bounds__(256) void proj_kernel(const float* __restrict__ q,
                                                   const float* __restrict__ k,
                                                   const float* __restrict__ v,
                                                   const float* __restrict__ Wq,
                                                   const float* __restrict__ Wk,
                                                   const float* __restrict__ Wv,
                                                   float* __restrict__ ap) {
  __shared__ float Xs[64 * 64];  // [cc][hw]
  const int br = blockIdx.z;
  const float* x = br == 0 ? q : (br == 1 ? k : v);
  const float* w = br == 0 ? Wq : (br == 1 ? Wk : Wv);
  float* apo = ap + (size_t)br * HW * 512;
  const int hw0 = blockIdx.x * 64;
  const int b = blockIdx.y;
  const int tid = threadIdx.x;
  const int lane = tid & 63;
  const int sq = __builtin_amdgcn_readfirstlane(tid >> 6);  // wave id 0..3 -> s group
  float acc[16] = {};
  for (int c0 = 0; c0 < CCH; c0 += 64) {
    __syncthreads();
#pragma unroll
    for (int it = 0; it < 4; ++it) {
      int f = (it * 256 + tid) * 4;
      int cc = f >> 6, i = f & 63;
      *reinterpret_cast<float4*>(&Xs[f]) =
          *reinterpret_cast<const float4*>(&x[(size_t)(b * CCH + c0 + cc) * HW + hw0 + i]);
    }
    __syncthreads();
#pragma unroll 2
    for (int cq = 0; cq < 64; cq += 4) {
      float x0 = Xs[(cq + 0) * 64 + lane];
      float x1 = Xs[(cq + 1) * 64 + lane];
      float x2 = Xs[(cq + 2) * 64 + lane];
      float x3 = Xs[(cq + 3) * 64 + lane];
#pragma unroll
      for (int j = 0; j < 16; ++j) {
        const float4 wv = *reinterpret_cast<const float4*>(&w[(size_t)(sq * 16 + j) * CCH + c0 + cq]);
        acc[j] = fmaf(x3, wv.w, fmaf(x2, wv.z, fmaf(x1, wv.y, fmaf(x0, wv.x, acc[j]))));
      }
    }
  }
  float* dst = &apo[(size_t)(hw0 + lane) * (BDIM * SDIM) + b * SDIM + sq * 16];
#pragma unroll
  for (int j4 = 0; j4 < 4; ++j4) {
    float4 o = make_float4(acc[j4 * 4 + 0], acc[j4 * 4 + 1], acc[j4 * 4 + 2], acc[j4 * 4 + 3]);
    *reinterpret_cast<float4*>(&dst[j4 * 4]) = o;
  }
}

// K2: rD[br][h][s][t] = 1 / sum_w exp( sum_b A[h,w,b,s]*B[h,w,b,t] )
__global__ __launch_bounds__(512) void denom_kernel(const float* __restrict__ ap,
                                                    float* __restrict__ rD) {
  __shared__ float As[8 * 64];
  __shared__ float Bs[8 * 64];
  const int h = blockIdx.x, br = blockIdx.y;
  const float* A  = ap + ((size_t)br * HW + (size_t)h * 64) * (BDIM * SDIM);
  const float* Bp = ap + ((size_t)((br + 1) % 3) * HW + (size_t)h * 64) * (BDIM * SDIM);
  const int tid = threadIdx.x;
  const int t = tid & 63;
  const int sb = (tid >> 6) * 8;
  float D[8] = {};
  for (int w = 0; w < 64; ++w) {
    __syncthreads();
    As[tid] = A[w * (BDIM * SDIM) + tid];
    Bs[tid] = Bp[w * (BDIM * SDIM) + tid];
    __syncthreads();
    float bv[8];
#pragma unroll
    for (int b = 0; b < 8; ++b) bv[b] = Bs[b * 64 + t];
#pragma unroll
    for (int j = 0; j < 8; ++j) {
      float m = 0.f;
#pragma unroll
      for (int b = 0; b < 8; ++b) m = fmaf(As[b * 64 + sb + j], bv[b], m);
      D[j] += __expf(m);
    }
  }
#pragma unroll
  for (int j = 0; j < 8; ++j)
    rD[((size_t)(br * 64 + h) * 64 + sb + j) * 64 + t] = 1.0f / D[j];
}

// K3: on[br][hw][b][s] = o[s][b]/N[b], o = mtilde * C^T
__global__ __launch_bounds__(256) void attn_kernel(const float* __restrict__ ap,
                                                   const float* __restrict__ rD,
                                                   float* __restrict__ on) {
  __shared__ float As[8 * 64], Bs[8 * 64], Cs[8 * 64];
  __shared__ float Ms[64 * 68];  // [s][t] padded
  const int wc = blockIdx.x, h = blockIdx.y, br = blockIdx.z;
  const float* A  = ap + ((size_t)br * HW + h * 64) * 512;
  const float* Bp = ap + ((size_t)((br + 1) % 3) * HW + h * 64) * 512;
  const float* Cp = ap + ((size_t)((br + 2) % 3) * HW + h * 64) * 512;
  const float* rDp = rD + (size_t)(br * 64 + h) * 4096;  // [s][t]
  const int tid = threadIdx.x;
  for (int w = wc * 8; w < wc * 8 + 8; ++w) {
    __syncthreads();
#pragma unroll
    for (int it = 0; it < 2; ++it) {
      int idx = it * 256 + tid;
      As[idx] = A[w * 512 + idx];
      Bs[idx] = Bp[w * 512 + idx];
      Cs[idx] = Cp[w * 512 + idx];
    }
    __syncthreads();
    {
      const int t = tid & 63, sg = tid >> 6;
      float bv[8];
#pragma unroll
      for (int b = 0; b < 8; ++b) bv[b] = Bs[b * 64 + t];
#pragma unroll
      for (int j = 0; j < 16; ++j) {
        int s = sg * 16 + j;
        float m = 0.f;
#pragma unroll
        for (int b = 0; b < 8; ++b) m = fmaf(As[b * 64 + s], bv[b], m);
        Ms[s * 68 + t] = __expf(m) * rDp[s * 64 + t];
      }
    }
    __syncthreads();
    const int s2 = tid & 63, bq = tid >> 6;
    float o0 = 0.f, o1 = 0.f;
#pragma unroll
    for (int tt = 0; tt < 64; tt += 4) {
      float4 mv = *reinterpret_cast<const float4*>(&Ms[s2 * 68 + tt]);
      float4 c0 = *reinterpret_cast<const float4*>(&Cs[bq * 64 + tt]);
      float4 c1 = *reinterpret_cast<const float4*>(&Cs[(bq + 4) * 64 + tt]);
      o0 = fmaf(mv.w, c0.w, fmaf(mv.z, c0.z, fmaf(mv.y, c0.y, fmaf(mv.x, c0.x, o0))));
      o1 = fmaf(mv.w, c1.w, fmaf(mv.z, c1.z, fmaf(mv.y, c1.y, fmaf(mv.x, c1.x, o1))));
    }
    // N[b] = sum_s o[s][b]  (butterfly over the 64 lanes = s)
    float n0 = o0, n1 = o1;
#pragma unroll
    for (int off = 32; off > 0; off >>= 1) {
      n0 += __shfl_xor(n0, off);
      n1 += __shfl_xor(n1, off);
    }
    const float r0 = 1.0f / n0, r1 = 1.0f / n1;
    const size_t ob = ((size_t)br * HW + h * 64 + w) * 512;
    on[ob + (size_t)bq * 64 + s2] = o0 * r0;
    on[ob + (size_t)(bq + 4) * 64 + s2] = o1 * r1;
  }
}

// K4: out[brb][c][hw] = sum_s on[br][hw][b][s] * wl[c][s]
__global__ __launch_bounds__(256) void out_kernel(const float* __restrict__ on,
                                                  const float* __restrict__ wl,
                                                  float* __restrict__ out) {
  __shared__ float Ol[64 * 68];  // [hw][s] padded
  const int c0 = blockIdx.x * 64;
  const int hw0 = blockIdx.y * 64;
  const int brb = blockIdx.z;
  const int br = brb >> 3, b = brb & 7;
  const int tid = threadIdx.x;
  const int lane = tid & 63;
  const int cq = __builtin_amdgcn_readfirstlane(tid >> 6);
#pragma unroll
  for (int it = 0; it < 4; ++it) {
    int f = (it * 256 + tid) * 4;
    int i = f >> 6, s = f & 63;
    *reinterpret_cast<float4*>(&Ol[i * 68 + s]) =
        *reinterpret_cast<const float4*>(&on[((size_t)(br * HW + hw0 + i) * 8 + b) * 64 + s]);
  }
  __syncthreads();
  float4 orow[16];
#pragma unroll
  for (int qd = 0; qd < 16; ++qd)
    orow[qd] = *reinterpret_cast<const float4*>(&Ol[lane * 68 + qd * 4]);
  float acc[16];
#pragma unroll
  for (int j = 0; j < 16; ++j) {
    const float* wrow = &wl[(size_t)(c0 + cq * 16 + j) * 64];
    float a = 0.f;
#pragma unroll
    for (int qd = 0; qd < 16; ++qd) {
      float4 wv = *reinterpret_cast<const float4*>(&wrow[qd * 4]);
      a = fmaf(orow[qd].w, wv.w, fmaf(orow[qd].z, wv.z, fmaf(orow[qd].y, wv.y, fmaf(orow[qd].x, wv.x, a))));
    }
    acc[j] = a;
  }
#pragma unroll
  for (int j = 0; j < 16; ++j)
    out[((size_t)brb * 512 + c0 + cq * 16 + j) * HW + hw0 + lane] = acc[j];
}

extern "C" void kernel_launch(void* const* d_in, const int* in_sizes, int n_in,
                              void* d_out, int out_size, void* d_ws, size_t ws_size,
                              hipStream_t stream) {
  const float* q  = (const float*)d_in[0];
  const float* k  = (const float*)d_in[1];
  const float* v  = (const float*)d_in[2];
  const float* Wq = (const float*)d_in[3];
  const float* Wk = (const float*)d_in[4];
  const float* Wv = (const float*)d_in[5];
  const float* Wl = (const float*)d_in[6];
  float* out = (float*)d_out;

  float* ap = (float*)d_ws;                         // 3*HW*B*S floats = 25.2 MB
  float* rD = ap + (size_t)3 * HW * 512;            // 3*64*64*64 floats = 3.1 MB
  float* on = rD + (size_t)3 * 64 * 64 * 64;        // 3*HW*B*S floats = 25.2 MB

  proj_kernel<<<dim3(64, 8, 3), 256, 0, stream>>>(q, k, v, Wq, Wk, Wv, ap);
  denom_kernel<<<dim3(64, 3), 512, 0, stream>>>(ap, rD);
  attn_kernel<<<dim3(8, 64, 3), 256, 0, stream>>>(ap, rD, on);
  out_kernel<<<dim3(8, 64, 24), 256, 0, stream>>>(on, Wl, out);
}

// Round 6
// 336.905 us; speedup vs baseline: 1.6696x; 1.1865x over previous
//
#include <hip/hip_runtime.h>
#include <hip/hip_bf16.h>

#define HW 4096
#define CCH 512
#define SDIM 64
#define BDIM 8
#define KPAD 72

typedef __attribute__((ext_vector_type(8))) short short8;
typedef __attribute__((ext_vector_type(4))) float f32x4;

static __device__ __forceinline__ ushort f2bf(float f) {
  __hip_bfloat16 h = __float2bfloat16(f);  // RNE
  return *reinterpret_cast<ushort*>(&h);
}
static __device__ __forceinline__ float bf2f(ushort u) {
  union { unsigned int u32; float f; } c;
  c.u32 = ((unsigned int)u) << 16;
  return c.f;
}

// K0: split the three projection weights into bf16 hi/mid/lo triples [br][s][c]
__global__ __launch_bounds__(256) void prep_kernel(const float* __restrict__ Wq,
                                                   const float* __restrict__ Wk,
                                                   const float* __restrict__ Wv,
                                                   ushort* __restrict__ whi,
                                                   ushort* __restrict__ wmid,
                                                   ushort* __restrict__ wlo) {
  const float* W = blockIdx.y == 0 ? Wq : (blockIdx.y == 1 ? Wk : Wv);
  const int idx = blockIdx.x * 1024 + threadIdx.x * 4;
  float4 f = *reinterpret_cast<const float4*>(&W[idx]);
  ushort4 h, m, l;
  float r, r2;
  h.x = f2bf(f.x); r = f.x - bf2f(h.x); m.x = f2bf(r); r2 = r - bf2f(m.x); l.x = f2bf(r2);
  h.y = f2bf(f.y); r = f.y - bf2f(h.y); m.y = f2bf(r); r2 = r - bf2f(m.y); l.y = f2bf(r2);
  h.z = f2bf(f.z); r = f.z - bf2f(h.z); m.z = f2bf(r); r2 = r - bf2f(m.z); l.z = f2bf(r2);
  h.w = f2bf(f.w); r = f.w - bf2f(h.w); m.w = f2bf(r); r2 = r - bf2f(m.w); l.w = f2bf(r2);
  const size_t o = (size_t)blockIdx.y * (SDIM * CCH) + idx;
  *reinterpret_cast<ushort4*>(&whi[o])  = h;
  *reinterpret_cast<ushort4*>(&wmid[o]) = m;
  *reinterpret_cast<ushort4*>(&wlo[o])  = l;
}

// K1: 3-way-split bf16 MFMA projection, Ootomo-style TWO accumulators:
//   acc_hi <- hh ; acc_cor <- hm+mh+mm+hl+lh+ml+lm ; A = acc_hi + acc_cor
//   ap[br][hw][b][s] = sum_c x_br[b][c][hw] * w_br[s][c]
__global__ __launch_bounds__(256) void proj_mfma_kernel(const float* __restrict__ q,
                                                        const float* __restrict__ k,
                                                        const float* __restrict__ v,
                                                        const ushort* __restrict__ whi,
                                                        const ushort* __restrict__ wmid,
                                                        const ushort* __restrict__ wlo,
                                                        float* __restrict__ ap) {
  __shared__ ushort Xh[128 * KPAD];
  __shared__ ushort Xm[128 * KPAD];
  __shared__ ushort Xl[128 * KPAD];
  const int mt = blockIdx.x;   // hw tile of 128
  const int b = blockIdx.y;
  const int br = blockIdx.z;
  const float* x = br == 0 ? q : (br == 1 ? k : v);
  const ushort* wh = whi + (size_t)br * SDIM * CCH;
  const ushort* wm = wmid + (size_t)br * SDIM * CCH;
  const ushort* wl = wlo + (size_t)br * SDIM * CCH;
  float* apo = ap + (size_t)br * HW * 512;
  const int hw0 = mt * 128;
  const int tid = threadIdx.x;
  const int l = tid & 63;
  const int wstrip = (tid >> 6) * 32;  // wave's 32-row m-strip
  const int row16 = l & 15;
  const int kgrp = l >> 4;
  const int mstage = tid & 127;        // staging: one m row per thread
  const int khalf = tid >> 7;          // staging: which 32-c half

  f32x4 acc_hi[2][4] = {};
  f32x4 acc_co[2][4] = {};

  for (int c0 = 0; c0 < CCH; c0 += 64) {
    __syncthreads();
    // stage A tile [128 m][64 k] as hi/mid/lo bf16, transposed from x's [k][m] layout
    float xv[32];
    const float* xp = x + ((size_t)b * CCH + c0 + khalf * 32) * HW + hw0 + mstage;
#pragma unroll
    for (int i = 0; i < 32; ++i) xv[i] = xp[(size_t)i * HW];
    ushort* dh = &Xh[mstage * KPAD + khalf * 32];
    ushort* dm = &Xm[mstage * KPAD + khalf * 32];
    ushort* dl = &Xl[mstage * KPAD + khalf * 32];
#pragma unroll
    for (int j = 0; j < 4; ++j) {
      ushort th[8], tm[8], tl[8];
#pragma unroll
      for (int i = 0; i < 8; ++i) {
        float f = xv[j * 8 + i];
        ushort h = f2bf(f);
        float r = f - bf2f(h);
        ushort mm = f2bf(r);
        float r2 = r - bf2f(mm);
        th[i] = h; tm[i] = mm; tl[i] = f2bf(r2);
      }
      *reinterpret_cast<short8*>(&dh[j * 8]) = *reinterpret_cast<const short8*>(th);
      *reinterpret_cast<short8*>(&dm[j * 8]) = *reinterpret_cast<const short8*>(tm);
      *reinterpret_cast<short8*>(&dl[j * 8]) = *reinterpret_cast<const short8*>(tl);
    }
    __syncthreads();
#pragma unroll
    for (int ks = 0; ks < 2; ++ks) {
      short8 ah[2], am[2], al[2], bh[4], bm[4], bl[4];
#pragma unroll
      for (int mf = 0; mf < 2; ++mf) {
        const int off = (wstrip + mf * 16 + row16) * KPAD + ks * 32 + kgrp * 8;
        ah[mf] = *reinterpret_cast<const short8*>(&Xh[off]);
        am[mf] = *reinterpret_cast<const short8*>(&Xm[off]);
        al[mf] = *reinterpret_cast<const short8*>(&Xl[off]);
      }
#pragma unroll
      for (int nf = 0; nf < 4; ++nf) {
        const size_t off = (size_t)(nf * 16 + row16) * CCH + c0 + ks * 32 + kgrp * 8;
        bh[nf] = *reinterpret_cast<const short8*>(&wh[off]);
        bm[nf] = *reinterpret_cast<const short8*>(&wm[off]);
        bl[nf] = *reinterpret_cast<const short8*>(&wl[off]);
      }
#pragma unroll
      for (int mf = 0; mf < 2; ++mf)
#pragma unroll
        for (int nf = 0; nf < 4; ++nf) {
          // dominant term -> its own accumulator (rounds at full scale only once/chunk)
          acc_hi[mf][nf] = __builtin_amdgcn_mfma_f32_16x16x32_bf16(ah[mf], bh[nf], acc_hi[mf][nf], 0, 0, 0);
          // correction terms -> separate accumulator (round at 2^-9 scale)
          acc_co[mf][nf] = __builtin_amdgcn_mfma_f32_16x16x32_bf16(ah[mf], bm[nf], acc_co[mf][nf], 0, 0, 0);
          acc_co[mf][nf] = __builtin_amdgcn_mfma_f32_16x16x32_bf16(am[mf], bh[nf], acc_co[mf][nf], 0, 0, 0);
          acc_co[mf][nf] = __builtin_amdgcn_mfma_f32_16x16x32_bf16(am[mf], bm[nf], acc_co[mf][nf], 0, 0, 0);
          acc_co[mf][nf] = __builtin_amdgcn_mfma_f32_16x16x32_bf16(ah[mf], bl[nf], acc_co[mf][nf], 0, 0, 0);
          acc_co[mf][nf] = __builtin_amdgcn_mfma_f32_16x16x32_bf16(al[mf], bh[nf], acc_co[mf][nf], 0, 0, 0);
          acc_co[mf][nf] = __builtin_amdgcn_mfma_f32_16x16x32_bf16(am[mf], bl[nf], acc_co[mf][nf], 0, 0, 0);
          acc_co[mf][nf] = __builtin_amdgcn_mfma_f32_16x16x32_bf16(al[mf], bm[nf], acc_co[mf][nf], 0, 0, 0);
        }
    }
  }
#pragma unroll
  for (int mf = 0; mf < 2; ++mf)
#pragma unroll
    for (int nf = 0; nf < 4; ++nf)
#pragma unroll
      for (int r = 0; r < 4; ++r) {
        const int m = hw0 + wstrip + mf * 16 + kgrp * 4 + r;
        apo[(size_t)m * 512 + b * 64 + nf * 16 + row16] = acc_hi[mf][nf][r] + acc_co[mf][nf][r];
      }
}

// K2: rD[br][h][s][t] = 1 / sum_w exp( sum_b A[h,w,b,s]*B[h,w,b,t] )
__global__ __launch_bounds__(512) void denom_kernel(const float* __restrict__ ap,
                                                    float* __restrict__ rD) {
  __shared__ float As[8 * 64];
  __shared__ float Bs[8 * 64];
  const int h = blockIdx.x, br = blockIdx.y;
  const float* A  = ap + ((size_t)br * HW + (size_t)h * 64) * (BDIM * SDIM);
  const float* Bp = ap + ((size_t)((br + 1) % 3) * HW + (size_t)h * 64) * (BDIM * SDIM);
  const int tid = threadIdx.x;
  const int t = tid & 63;
  const int sb = (tid >> 6) * 8;
  float D[8] = {};
  for (int w = 0; w < 64; ++w) {
    __syncthreads();
    As[tid] = A[w * (BDIM * SDIM) + tid];
    Bs[tid] = Bp[w * (BDIM * SDIM) + tid];
    __syncthreads();
    float bv[8];
#pragma unroll
    for (int b = 0; b < 8; ++b) bv[b] = Bs[b * 64 + t];
#pragma unroll
    for (int j = 0; j < 8; ++j) {
      float m = 0.f;
#pragma unroll
      for (int b = 0; b < 8; ++b) m = fmaf(As[b * 64 + sb + j], bv[b], m);
      D[j] += __expf(m);
    }
  }
#pragma unroll
  for (int j = 0; j < 8; ++j)
    rD[((size_t)(br * 64 + h) * 64 + sb + j) * 64 + t] = 1.0f / D[j];
}

// K3: on[br][hw][b][s] = o[s][b]/N[b], o = mtilde * C^T
__global__ __launch_bounds__(256) void attn_kernel(const float* __restrict__ ap,
                                                   const float* __restrict__ rD,
                                                   float* __restrict__ on) {
  __shared__ float As[8 * 64], Bs[8 * 64], Cs[8 * 64];
  __shared__ float Ms[64 * 68];  // [s][t] padded
  const int wc = blockIdx.x, h = blockIdx.y, br = blockIdx.z;
  const float* A  = ap + ((size_t)br * HW + h * 64) * 512;
  const float* Bp = ap + ((size_t)((br + 1) % 3) * HW + h * 64) * 512;
  const float* Cp = ap + ((size_t)((br + 2) % 3) * HW + h * 64) * 512;
  const float* rDp = rD + (size_t)(br * 64 + h) * 4096;  // [s][t]
  const int tid = threadIdx.x;
  for (int w = wc * 8; w < wc * 8 + 8; ++w) {
    __syncthreads();
#pragma unroll
    for (int it = 0; it < 2; ++it) {
      int idx = it * 256 + tid;
      As[idx] = A[w * 512 + idx];
      Bs[idx] = Bp[w * 512 + idx];
      Cs[idx] = Cp[w * 512 + idx];
    }
    __syncthreads();
    {
      const int t = tid & 63, sg = tid >> 6;
      float bv[8];
#pragma unroll
      for (int b = 0; b < 8; ++b) bv[b] = Bs[b * 64 + t];
#pragma unroll
      for (int j = 0; j < 16; ++j) {
        int s = sg * 16 + j;
        float m = 0.f;
#pragma unroll
        for (int b = 0; b < 8; ++b) m = fmaf(As[b * 64 + s], bv[b], m);
        Ms[s * 68 + t] = __expf(m) * rDp[s * 64 + t];
      }
    }
    __syncthreads();
    const int s2 = tid & 63, bq = tid >> 6;
    float o0 = 0.f, o1 = 0.f;
#pragma unroll
    for (int tt = 0; tt < 64; tt += 4) {
      float4 mv = *reinterpret_cast<const float4*>(&Ms[s2 * 68 + tt]);
      float4 c0 = *reinterpret_cast<const float4*>(&Cs[bq * 64 + tt]);
      float4 c1 = *reinterpret_cast<const float4*>(&Cs[(bq + 4) * 64 + tt]);
      o0 = fmaf(mv.w, c0.w, fmaf(mv.z, c0.z, fmaf(mv.y, c0.y, fmaf(mv.x, c0.x, o0))));
      o1 = fmaf(mv.w, c1.w, fmaf(mv.z, c1.z, fmaf(mv.y, c1.y, fmaf(mv.x, c1.x, o1))));
    }
    float n0 = o0, n1 = o1;
#pragma unroll
    for (int off = 32; off > 0; off >>= 1) {
      n0 += __shfl_xor(n0, off);
      n1 += __shfl_xor(n1, off);
    }
    const float r0 = 1.0f / n0, r1 = 1.0f / n1;
    const size_t ob = ((size_t)br * HW + h * 64 + w) * 512;
    on[ob + (size_t)bq * 64 + s2] = o0 * r0;
    on[ob + (size_t)(bq + 4) * 64 + s2] = o1 * r1;
  }
}

// K4: out[brb][c][hw] = sum_s on[br][hw][b][s] * wl[c][s]
__global__ __launch_bounds__(256) void out_kernel(const float* __restrict__ on,
                                                  const float* __restrict__ wl,
                                                  float* __restrict__ out) {
  __shared__ float Ol[64 * 68];  // [hw][s] padded
  const int c0 = blockIdx.x * 64;
  const int hw0 = blockIdx.y * 64;
  const int brb = blockIdx.z;
  const int br = brb >> 3, b = brb & 7;
  const int tid = threadIdx.x;
  const int lane = tid & 63;
  const int cq = __builtin_amdgcn_readfirstlane(tid >> 6);
#pragma unroll
  for (int it = 0; it < 4; ++it) {
    int f = (it * 256 + tid) * 4;
    int i = f >> 6, s = f & 63;
    *reinterpret_cast<float4*>(&Ol[i * 68 + s]) =
        *reinterpret_cast<const float4*>(&on[((size_t)(br * HW + hw0 + i) * 8 + b) * 64 + s]);
  }
  __syncthreads();
  float4 orow[16];
#pragma unroll
  for (int qd = 0; qd < 16; ++qd)
    orow[qd] = *reinterpret_cast<const float4*>(&Ol[lane * 68 + qd * 4]);
  float acc[16];
#pragma unroll
  for (int j = 0; j < 16; ++j) {
    const float* wrow = &wl[(size_t)(c0 + cq * 16 + j) * 64];
    float a = 0.f;
#pragma unroll
    for (int qd = 0; qd < 16; ++qd) {
      float4 wv = *reinterpret_cast<const float4*>(&wrow[qd * 4]);
      a = fmaf(orow[qd].w, wv.w, fmaf(orow[qd].z, wv.z, fmaf(orow[qd].y, wv.y, fmaf(orow[qd].x, wv.x, a))));
    }
    acc[j] = a;
  }
#pragma unroll
  for (int j = 0; j < 16; ++j)
    out[((size_t)brb * 512 + c0 + cq * 16 + j) * HW + hw0 + lane] = acc[j];
}

extern "C" void kernel_launch(void* const* d_in, const int* in_sizes, int n_in,
                              void* d_out, int out_size, void* d_ws, size_t ws_size,
                              hipStream_t stream) {
  const float* q  = (const float*)d_in[0];
  const float* k  = (const float*)d_in[1];
  const float* v  = (const float*)d_in[2];
  const float* Wq = (const float*)d_in[3];
  const float* Wk = (const float*)d_in[4];
  const float* Wv = (const float*)d_in[5];
  const float* Wl = (const float*)d_in[6];
  float* out = (float*)d_out;

  float* ap = (float*)d_ws;                         // 3*HW*B*S floats = 25.2 MB
  float* rD = ap + (size_t)3 * HW * 512;            // 3*64*64*64 floats = 3.1 MB
  float* on = rD + (size_t)3 * 64 * 64 * 64;        // 3*HW*B*S floats = 25.2 MB
  ushort* whi  = (ushort*)rD;                       // 3*64*512*2B = 192 KB, consumed before denom
  ushort* wmid = whi + (size_t)3 * SDIM * CCH;
  ushort* wlo  = wmid + (size_t)3 * SDIM * CCH;

  prep_kernel<<<dim3(32, 3), 256, 0, stream>>>(Wq, Wk, Wv, whi, wmid, wlo);
  proj_mfma_kernel<<<dim3(32, 8, 3), 256, 0, stream>>>(q, k, v, whi, wmid, wlo, ap);
  denom_kernel<<<dim3(64, 3), 512, 0, stream>>>(ap, rD);
  attn_kernel<<<dim3(8, 64, 3), 256, 0, stream>>>(ap, rD, on);
  out_kernel<<<dim3(8, 64, 24), 256, 0, stream>>>(on, Wl, out);
}